// Round 5
// baseline (133.496 us; speedup 1.0000x reference)
//
#include <hip/hip_runtime.h>
#include <math.h>

#define IN_NODES 1152
#define OUT_NODES 10
#define IN_DIM 8
#define OUT_DIM 16
#define BATCH 256
#define KTILES 288       // 9216 / 32  (K = i*8+k)
#define KC 16            // split-K chunks
#define KT_PER_KC 18     // 288 / 16

typedef __attribute__((ext_vector_type(8))) short bf16x8;
typedef __attribute__((ext_vector_type(4))) float f32x4;

__device__ __forceinline__ unsigned short f2bf(float f) {
    unsigned u = __float_as_uint(f);
    u += 0x7FFF + ((u >> 16) & 1);   // round-to-nearest-even
    return (unsigned short)(u >> 16);
}
__device__ __forceinline__ float bf2f(unsigned short h) {
    return __uint_as_float(((unsigned)h) << 16);
}

// async global->LDS, 16B per lane (used by k_agree)
__device__ __forceinline__ void ld16(const void* g, void* l) {
    __builtin_amdgcn_global_load_lds(
        (const __attribute__((address_space(1))) unsigned int*)g,
        (__attribute__((address_space(3))) unsigned int*)l, 16, 0, 0);
}

// ---------------------------------------------------------------------------
// prep: xr[i,b,k] = x[b,i,k]; blog=0; c=0.1
// ---------------------------------------------------------------------------
__global__ __launch_bounds__(256) void k_prep(const float* __restrict__ x,
                                              float* __restrict__ xr,
                                              float* __restrict__ blog,
                                              float* __restrict__ cbuf) {
    const int i = blockIdx.x;
    const int tid = threadIdx.x;
    const float4* src = (const float4*)(x + (size_t)tid * (IN_NODES * IN_DIM) +
                                        (size_t)i * IN_DIM);
    float4 a0 = src[0], a1 = src[1];
    float4* dst = (float4*)(xr + (size_t)i * (BATCH * IN_DIM) + (size_t)tid * IN_DIM);
    dst[0] = a0; dst[1] = a1;
    if (tid < OUT_NODES) {
        blog[i * OUT_NODES + tid] = 0.0f;
        cbuf[i * OUT_NODES + tid] = 1.0f / OUT_NODES;
    }
}

// ---------------------------------------------------------------------------
// B-pack (once): Bhi/Blo[bt][kt][lane][8] = bf16 split of x[b,i,kk]
//   b = bt*16 + (lane&15), i = kt*4 + (lane>>4), kk = e
// slot s = ((bt*KTILES)+kt)*64 + lane ; grid = 16*288*64/256 = 1152 blocks
// ---------------------------------------------------------------------------
__global__ __launch_bounds__(256) void k_prepB(const float* __restrict__ xr,
                                               unsigned short* __restrict__ Bhi,
                                               unsigned short* __restrict__ Blo) {
    const size_t s = (size_t)blockIdx.x * 256 + threadIdx.x;
    const int lane = (int)(s & 63);
    const size_t q = s >> 6;
    const int kt = (int)(q % KTILES);
    const int bt = (int)(q / KTILES);
    const int b = bt * 16 + (lane & 15);
    const int i = kt * 4 + (lane >> 4);

    const float4* xp = (const float4*)(xr + ((size_t)i * BATCH + b) * IN_DIM);
    float4 x0 = xp[0], x1 = xp[1];
    float vals[8] = {x0.x, x0.y, x0.z, x0.w, x1.x, x1.y, x1.z, x1.w};

    unsigned short hi[8], lo[8];
#pragma unroll
    for (int e = 0; e < 8; ++e) {
        hi[e] = f2bf(vals[e]);
        lo[e] = f2bf(vals[e] - bf2f(hi[e]));
    }
    bf16x8 vh, vl;
#pragma unroll
    for (int e = 0; e < 8; ++e) { vh[e] = (short)hi[e]; vl[e] = (short)lo[e]; }
    *(bf16x8*)(Bhi + s * 8) = vh;
    *(bf16x8*)(Blo + s * 8) = vl;
}

// ---------------------------------------------------------------------------
// A-fold (per iteration): Ahi/Alo[j][kt][lane][8] = bf16 split of c[i,j]*W[i,j,d,kk]
//   d = lane&15, i = kt*4 + (lane>>4), kk = e
// slot s = ((j*KTILES)+kt)*64 + lane ; grid = 10*288*64/256 = 720 blocks
// ---------------------------------------------------------------------------
__global__ __launch_bounds__(256) void k_fold(const float* __restrict__ W,
                                              const float* __restrict__ cbuf,
                                              unsigned short* __restrict__ Ahi,
                                              unsigned short* __restrict__ Alo) {
    const size_t s = (size_t)blockIdx.x * 256 + threadIdx.x;
    const int lane = (int)(s & 63);
    const size_t q = s >> 6;
    const int kt = (int)(q % KTILES);
    const int j = (int)(q / KTILES);
    const int d = lane & 15;
    const int i = kt * 4 + (lane >> 4);

    const float4* wp = (const float4*)(W + (((size_t)i * OUT_NODES + j) * OUT_DIM + d) * IN_DIM);
    float4 w0 = wp[0], w1 = wp[1];
    const float c = cbuf[i * OUT_NODES + j];
    float vals[8] = {c * w0.x, c * w0.y, c * w0.z, c * w0.w,
                     c * w1.x, c * w1.y, c * w1.z, c * w1.w};

    bf16x8 vh, vl;
#pragma unroll
    for (int e = 0; e < 8; ++e) {
        unsigned short h = f2bf(vals[e]);
        vh[e] = (short)h;
        vl[e] = (short)f2bf(vals[e] - bf2f(h));
    }
    *(bf16x8*)(Ahi + s * 8) = vh;
    *(bf16x8*)(Alo + s * 8) = vl;
}

// ---------------------------------------------------------------------------
// s-GEMM via MFMA 16x16x32 bf16, split-bf16 (3 cross terms).
// grid (j=10, btg=4, kc=16), 256 thr = 4 waves; wave w -> bt = btg*4+w.
// part[kc][j][d][b] = C-tile.  No LDS, no barriers.
// ---------------------------------------------------------------------------
__global__ __launch_bounds__(256) void k_s(const unsigned short* __restrict__ Ahi,
                                           const unsigned short* __restrict__ Alo,
                                           const unsigned short* __restrict__ Bhi,
                                           const unsigned short* __restrict__ Blo,
                                           float* __restrict__ part) {
    const int j = blockIdx.x;
    const int btg = blockIdx.y;
    const int kc = blockIdx.z;
    const int w = threadIdx.x >> 6;
    const int lane = threadIdx.x & 63;
    const int bt = btg * 4 + w;

    const size_t abase = (((size_t)j * KTILES + kc * KT_PER_KC) * 64 + lane) * 8;
    const size_t bbase = (((size_t)bt * KTILES + kc * KT_PER_KC) * 64 + lane) * 8;

    f32x4 acc = {0.f, 0.f, 0.f, 0.f};
#pragma unroll 3
    for (int t = 0; t < KT_PER_KC; ++t) {
        bf16x8 ah = *(const bf16x8*)(Ahi + abase + (size_t)t * 512);
        bf16x8 al = *(const bf16x8*)(Alo + abase + (size_t)t * 512);
        bf16x8 bh = *(const bf16x8*)(Bhi + bbase + (size_t)t * 512);
        bf16x8 bl = *(const bf16x8*)(Blo + bbase + (size_t)t * 512);
        acc = __builtin_amdgcn_mfma_f32_16x16x32_bf16(ah, bh, acc, 0, 0, 0);
        acc = __builtin_amdgcn_mfma_f32_16x16x32_bf16(ah, bl, acc, 0, 0, 0);
        acc = __builtin_amdgcn_mfma_f32_16x16x32_bf16(al, bh, acc, 0, 0, 0);
    }

    const int d0 = (lane >> 4) * 4;        // C row = d
    const int b = bt * 16 + (lane & 15);   // C col = b
#pragma unroll
    for (int r = 0; r < 4; ++r)
        part[(((size_t)kc * OUT_NODES + j) * OUT_DIM + d0 + r) * BATCH + b] = acc[r];
}

// ---------------------------------------------------------------------------
// Reduce over KC + squash. grid (10 j, 8 b-groups), 512 thr (16d x 32b).
// ---------------------------------------------------------------------------
__global__ __launch_bounds__(512) void k_reduce_squash(const float* __restrict__ part,
                                                       float* __restrict__ v,
                                                       float* __restrict__ out,
                                                       int write_out) {
    const int j = blockIdx.x;
    const int t = threadIdx.x;
    const int d = t & 15;
    const int b = blockIdx.y * 32 + (t >> 4);

    float s = 0.f;
#pragma unroll
    for (int kc = 0; kc < KC; ++kc)
        s += part[(((size_t)kc * OUT_NODES + j) * OUT_DIM + d) * BATCH + b];

    float sq = s * s;
    sq += __shfl_xor(sq, 1);
    sq += __shfl_xor(sq, 2);
    sq += __shfl_xor(sq, 4);
    sq += __shfl_xor(sq, 8);
    float scale = sq / ((1.0f + sq) * sqrtf(sq));
    float vv = s * scale;
    v[((size_t)j * BATCH + b) * OUT_DIM + d] = vv;
    if (write_out) out[((size_t)b * OUT_NODES + j) * OUT_DIM + d] = vv;
}

// ---------------------------------------------------------------------------
// Agreement + b-logit update + softmax. grid 1152, 256 threads (b-parallel).
// ---------------------------------------------------------------------------
__global__ __launch_bounds__(256) void k_agree(const float* __restrict__ W,
                                               const float* __restrict__ xr,
                                               const float* __restrict__ v,
                                               float* __restrict__ blog,
                                               float* __restrict__ cbuf) {
    __shared__ __align__(16) float W_s[1280];
    __shared__ float red[4][OUT_NODES];
    __shared__ float bsh[OUT_NODES];

    const int i = blockIdx.x;
    const int tid = threadIdx.x;
    const int w = tid >> 6, lane = tid & 63;

    {
        const char* gw = (const char*)W + (size_t)i * 5120 + w * 1280 + lane * 16;
        char* lw = (char*)&W_s[0] + w * 1280 + lane * 16;
        ld16(gw, lw);
        if (lane < 16) ld16(gw + 1024, lw + 1024);
    }
    asm volatile("s_waitcnt vmcnt(0)" ::: "memory");
    __syncthreads();

    const int b = tid;
    const float4* xp = (const float4*)(xr + ((size_t)i * BATCH + b) * IN_DIM);
    const float4 x0 = xp[0], x1 = xp[1];

#pragma unroll 2
    for (int j = 0; j < OUT_NODES; ++j) {
        const float4* vp = (const float4*)(v + ((size_t)j * BATCH + b) * OUT_DIM);
        float4 v0 = vp[0], v1 = vp[1], v2 = vp[2], v3 = vp[3];
        float vv[16] = {v0.x, v0.y, v0.z, v0.w, v1.x, v1.y, v1.z, v1.w,
                        v2.x, v2.y, v2.z, v2.w, v3.x, v3.y, v3.z, v3.w};
        float s0 = 0.f, s1 = 0.f, s2 = 0.f, s3 = 0.f;
#pragma unroll
        for (int d = 0; d < OUT_DIM; ++d) {
            float4 w0 = *(const float4*)&W_s[(j * 16 + d) * 8];
            float4 w1 = *(const float4*)&W_s[(j * 16 + d) * 8 + 4];
            float u = w0.x * x0.x;
            u = fmaf(w0.y, x0.y, u); u = fmaf(w0.z, x0.z, u);
            u = fmaf(w0.w, x0.w, u); u = fmaf(w1.x, x1.x, u);
            u = fmaf(w1.y, x1.y, u); u = fmaf(w1.z, x1.z, u);
            u = fmaf(w1.w, x1.w, u);
            if ((d & 3) == 0) s0 = fmaf(u, vv[d], s0);
            else if ((d & 3) == 1) s1 = fmaf(u, vv[d], s1);
            else if ((d & 3) == 2) s2 = fmaf(u, vv[d], s2);
            else s3 = fmaf(u, vv[d], s3);
        }
        float sum = (s0 + s1) + (s2 + s3);
        sum += __shfl_xor(sum, 1);
        sum += __shfl_xor(sum, 2);
        sum += __shfl_xor(sum, 4);
        sum += __shfl_xor(sum, 8);
        sum += __shfl_xor(sum, 16);
        sum += __shfl_xor(sum, 32);
        if (lane == 0) red[w][j] = sum;
    }
    __syncthreads();

    if (tid < OUT_NODES) {
        float a = red[0][tid] + red[1][tid] + red[2][tid] + red[3][tid];
        float bn = blog[i * OUT_NODES + tid] + a * (1.0f / BATCH);
        blog[i * OUT_NODES + tid] = bn;
        bsh[tid] = bn;
    }
    __syncthreads();

    if (tid < OUT_NODES) {
        float m = bsh[0];
#pragma unroll
        for (int jj = 1; jj < OUT_NODES; ++jj) m = fmaxf(m, bsh[jj]);
        float ssum = 0.f;
#pragma unroll
        for (int jj = 0; jj < OUT_NODES; ++jj) ssum += __expf(bsh[jj] - m);
        cbuf[i * OUT_NODES + tid] = __expf(bsh[tid] - m) / ssum;
    }
}

// ---------------------------------------------------------------------------
extern "C" void kernel_launch(void* const* d_in, const int* in_sizes, int n_in,
                              void* d_out, int out_size, void* d_ws, size_t ws_size,
                              hipStream_t stream) {
    const float* x = (const float*)d_in[0];  // [256,1152,8]
    const float* W = (const float*)d_in[1];  // [1152,10,16,8]
    float* out = (float*)d_out;              // [256,10,16,1]

    char* p = (char*)d_ws;
    float* xr = (float*)p;            p += (size_t)IN_NODES * BATCH * IN_DIM * 4;   // 9.44 MB
    float* part = (float*)p;          p += (size_t)KC * OUT_NODES * OUT_DIM * BATCH * 4; // 2.62 MB
    float* v = (float*)p;             p += (size_t)OUT_NODES * BATCH * OUT_DIM * 4;
    float* blog = (float*)p;          p += (size_t)IN_NODES * OUT_NODES * 4;
    float* cbuf = (float*)p;          p += (size_t)IN_NODES * OUT_NODES * 4;
    unsigned short* Ahi = (unsigned short*)p; p += (size_t)OUT_NODES * KTILES * 64 * 8 * 2; // 2.95 MB
    unsigned short* Alo = (unsigned short*)p; p += (size_t)OUT_NODES * KTILES * 64 * 8 * 2;
    unsigned short* Bhi = (unsigned short*)p; p += (size_t)16 * KTILES * 64 * 8 * 2;        // 4.72 MB
    unsigned short* Blo = (unsigned short*)p; p += (size_t)16 * KTILES * 64 * 8 * 2;

    k_prep<<<IN_NODES, 256, 0, stream>>>(x, xr, blog, cbuf);
    k_prepB<<<1152, 256, 0, stream>>>(xr, Bhi, Blo);

    for (int it = 0; it < 3; ++it) {
        k_fold<<<720, 256, 0, stream>>>(W, cbuf, Ahi, Alo);
        k_s<<<dim3(OUT_NODES, 4, KC), 256, 0, stream>>>(Ahi, Alo, Bhi, Blo, part);
        k_reduce_squash<<<dim3(OUT_NODES, 8), 512, 0, stream>>>(part, v, out,
                                                                it == 2 ? 1 : 0);
        if (it < 2) k_agree<<<IN_NODES, 256, 0, stream>>>(W, xr, v, blog, cbuf);
    }
}